// Round 6
// baseline (305.311 us; speedup 1.0000x reference)
//
#include <hip/hip_runtime.h>
#include <cmath>

// Problem constants: B=32768, N=17, D=2, K=3, H=64 (bMLP hidden=128, out=12)
#define NBATCH 32768
#define NJOINT 17
#define OUT0_ELEMS (NBATCH * NJOINT * 15)          // out[B,N,3,5]
#define KJS_OFF    OUT0_ELEMS                      // k_js[B,N]
#define MASK_OFF   (KJS_OFF + NBATCH * NJOINT)     // mask[B,N,3]

__device__ __forceinline__ float sel3f(int i, float a, float b, float c) {
    return (i == 0) ? a : ((i == 1) ? b : c);
}

// Force a pointer into VGPRs via opaque inline asm. Inline-asm results are
// conservatively divergent -> all derived loads take the VECTOR memory path
// (global_load_dwordx4, in-order, fine-grained vmcnt) instead of SMEM s_load
// (out-of-order, full lgkmcnt(0) drain before every use — the R1-R5 stall).
// All lanes load the same address -> TA coalesces to one request, broadcast.
__device__ __forceinline__ const float* vlaunder(const float* p) {
    unsigned long long v = (unsigned long long)p;
    asm("" : "+v"(v));
    return (const float*)v;
}

// Cold path: exact fp64 recompute of a 2->64->3 MLP. Taken only when fp32
// logits have a near-tie (< 1e-4 rel) that could flip argmax/argsort.
__device__ __noinline__ void mlp64_small(
    const float* __restrict__ W1a, const float* __restrict__ W1b,
    const float* __restrict__ b1,  const float* __restrict__ W2,
    const float* __restrict__ b2,
    double x0, double x1, double& l0, double& l1, double& l2)
{
    l0 = (double)b2[0]; l1 = (double)b2[1]; l2 = (double)b2[2];
    for (int h = 0; h < 64; ++h) {
        double hv = fma(x1, (double)W1b[h], fma(x0, (double)W1a[h], (double)b1[h]));
        hv = fmax(hv, 0.0);
        l0 = fma(hv, (double)W2[h * 3 + 0], l0);
        l1 = fma(hv, (double)W2[h * 3 + 1], l1);
        l2 = fma(hv, (double)W2[h * 3 + 2], l2);
    }
}

__global__ __launch_bounds__(128) void mdn_fused(
    const float* __restrict__ pred_pts,
    const float* __restrict__ kW1, const float* __restrict__ kb1,
    const float* __restrict__ kW2, const float* __restrict__ kb2,
    const float* __restrict__ wW1, const float* __restrict__ wb1,
    const float* __restrict__ wW2, const float* __restrict__ wb2,
    const float* __restrict__ bW1, const float* __restrict__ bb1,
    const float* __restrict__ bW2, const float* __restrict__ bb2,
    float* __restrict__ out)
{
    const int n = blockIdx.y;
    const int b = blockIdx.x * 128 + threadIdx.x;
    const int p = b * NJOINT + n;

    const float2 xv = *reinterpret_cast<const float2*>(pred_pts + 2 * p);
    const float x0f = xv.x, x1f = xv.y;

    // Laundered (vector-path) weight bases
    const float* kW1v = vlaunder(kW1 + n * 128);
    const float* kb1v = vlaunder(kb1 + n * 64);
    const float* kW2v = vlaunder(kW2 + n * 192);
    const float* wW1v = vlaunder(wW1 + n * 128);
    const float* wb1v = vlaunder(wb1 + n * 64);
    const float* wW2v = vlaunder(wW2 + n * 192);
    const float* bW1v = vlaunder(bW1 + n * 256);
    const float* bb1v = vlaunder(bb1 + n * 128);
    const float* bW2v = vlaunder(bW2 + n * 1536);

    // -------- merged kMLP + wMLP : 2 -> 64 -> 3, fp32, float4 loads --------
    float kf0 = kb2[n * 3 + 0], kf1 = kb2[n * 3 + 1], kf2 = kb2[n * 3 + 2];
    float wf0 = wb2[n * 3 + 0], wf1 = wb2[n * 3 + 1], wf2 = wb2[n * 3 + 2];
    #pragma unroll 2
    for (int h = 0; h < 64; h += 4) {
        const float4 ka = *reinterpret_cast<const float4*>(kW1v + h);
        const float4 kb_ = *reinterpret_cast<const float4*>(kW1v + 64 + h);
        const float4 kbi = *reinterpret_cast<const float4*>(kb1v + h);
        const float4 kq0 = *reinterpret_cast<const float4*>(kW2v + 3 * h);
        const float4 kq1 = *reinterpret_cast<const float4*>(kW2v + 3 * h + 4);
        const float4 kq2 = *reinterpret_cast<const float4*>(kW2v + 3 * h + 8);
        const float4 wa = *reinterpret_cast<const float4*>(wW1v + h);
        const float4 wb_ = *reinterpret_cast<const float4*>(wW1v + 64 + h);
        const float4 wbi = *reinterpret_cast<const float4*>(wb1v + h);
        const float4 wq0 = *reinterpret_cast<const float4*>(wW2v + 3 * h);
        const float4 wq1 = *reinterpret_cast<const float4*>(wW2v + 3 * h + 4);
        const float4 wq2 = *reinterpret_cast<const float4*>(wW2v + 3 * h + 8);

        float hv;
        hv = fmaxf(fmaf(x1f, kb_.x, fmaf(x0f, ka.x, kbi.x)), 0.0f);
        kf0 = fmaf(hv, kq0.x, kf0); kf1 = fmaf(hv, kq0.y, kf1); kf2 = fmaf(hv, kq0.z, kf2);
        hv = fmaxf(fmaf(x1f, kb_.y, fmaf(x0f, ka.y, kbi.y)), 0.0f);
        kf0 = fmaf(hv, kq0.w, kf0); kf1 = fmaf(hv, kq1.x, kf1); kf2 = fmaf(hv, kq1.y, kf2);
        hv = fmaxf(fmaf(x1f, kb_.z, fmaf(x0f, ka.z, kbi.z)), 0.0f);
        kf0 = fmaf(hv, kq1.z, kf0); kf1 = fmaf(hv, kq1.w, kf1); kf2 = fmaf(hv, kq2.x, kf2);
        hv = fmaxf(fmaf(x1f, kb_.w, fmaf(x0f, ka.w, kbi.w)), 0.0f);
        kf0 = fmaf(hv, kq2.y, kf0); kf1 = fmaf(hv, kq2.z, kf1); kf2 = fmaf(hv, kq2.w, kf2);

        hv = fmaxf(fmaf(x1f, wb_.x, fmaf(x0f, wa.x, wbi.x)), 0.0f);
        wf0 = fmaf(hv, wq0.x, wf0); wf1 = fmaf(hv, wq0.y, wf1); wf2 = fmaf(hv, wq0.z, wf2);
        hv = fmaxf(fmaf(x1f, wb_.y, fmaf(x0f, wa.y, wbi.y)), 0.0f);
        wf0 = fmaf(hv, wq0.w, wf0); wf1 = fmaf(hv, wq1.x, wf1); wf2 = fmaf(hv, wq1.y, wf2);
        hv = fmaxf(fmaf(x1f, wb_.z, fmaf(x0f, wa.z, wbi.z)), 0.0f);
        wf0 = fmaf(hv, wq1.z, wf0); wf1 = fmaf(hv, wq1.w, wf1); wf2 = fmaf(hv, wq2.x, wf2);
        hv = fmaxf(fmaf(x1f, wb_.w, fmaf(x0f, wa.w, wbi.w)), 0.0f);
        wf0 = fmaf(hv, wq2.y, wf0); wf1 = fmaf(hv, wq2.z, wf1); wf2 = fmaf(hv, wq2.w, wf2);
    }

    // k argmax with fp64 fallback on near-tie
    double kl0 = (double)kf0, kl1 = (double)kf1, kl2 = (double)kf2;
    {
        const float d01 = fabsf(kf0 - kf1), d02 = fabsf(kf0 - kf2), d12 = fabsf(kf1 - kf2);
        const float sc = fmaxf(fmaxf(fabsf(kf0), fabsf(kf1)), fabsf(kf2));
        if (fminf(fminf(d01, d02), d12) < 1e-4f * fmaxf(sc, 1.0f))
            mlp64_small(kW1 + n * 128, kW1 + n * 128 + 64, kb1 + n * 64,
                        kW2 + n * 192, kb2 + n * 3,
                        (double)x0f, (double)x1f, kl0, kl1, kl2);
    }
    int kj = 0;  // first-occurrence argmax (jnp.argmax semantics)
    {
        double m = kl0;
        if (kl1 > m) { m = kl1; kj = 1; }
        if (kl2 > m) { kj = 2; }
    }

    // w argsort with fp64 fallback on near-tie
    double wl0 = (double)wf0, wl1 = (double)wf1, wl2 = (double)wf2;
    {
        const float d01 = fabsf(wf0 - wf1), d02 = fabsf(wf0 - wf2), d12 = fabsf(wf1 - wf2);
        const float sc = fmaxf(fmaxf(fabsf(wf0), fabsf(wf1)), fabsf(wf2));
        if (fminf(fminf(d01, d02), d12) < 1e-4f * fmaxf(sc, 1.0f))
            mlp64_small(wW1 + n * 128, wW1 + n * 128 + 64, wb1 + n * 64,
                        wW2 + n * 192, wb2 + n * 3,
                        (double)x0f, (double)x1f, wl0, wl1, wl2);
    }
    // stable descending argsort of 3 (jnp.argsort(-w): ties -> lower index first)
    int i0 = 0;
    {
        double m = wl0;
        if (wl1 > m) { m = wl1; i0 = 1; }
        if (wl2 > m) { i0 = 2; }
    }
    const int ia = (i0 == 0) ? 1 : 0;
    const int ib = (i0 == 2) ? 1 : 2;
    const double wa2 = ia ? wl1 : wl0;
    const double wb2_ = (ib == 1) ? wl1 : wl2;
    const int i1 = (wb2_ > wa2) ? ib : ia;
    const int i2 = (wb2_ > wa2) ? ia : ib;

    // softmax from fp32 logits (2% tolerance; fp32 error ~1e-6)
    const float mw = fmaxf(fmaxf(wf0, wf1), wf2);
    const float e0 = __expf(wf0 - mw);
    const float e1 = __expf(wf1 - mw);
    const float e2 = __expf(wf2 - mw);
    const float inv = 1.0f / (e0 + e1 + e2);
    const float p0 = e0 * inv, p1 = e1 * inv, p2 = e2 * inv;

    // ---------------- bMLP : 2 -> 128 -> 12, fp32, float4 loads ------------
    float acc[12];
    {
        const float* b2 = bb2 + n * 12;
        #pragma unroll
        for (int j = 0; j < 12; ++j) acc[j] = b2[j];
        #pragma unroll 2
        for (int h = 0; h < 128; h += 4) {
            const float4 a4 = *reinterpret_cast<const float4*>(bW1v + h);
            const float4 b4 = *reinterpret_cast<const float4*>(bW1v + 128 + h);
            const float4 c4 = *reinterpret_cast<const float4*>(bb1v + h);
            const float hv0 = fmaxf(fmaf(x1f, b4.x, fmaf(x0f, a4.x, c4.x)), 0.0f);
            const float hv1 = fmaxf(fmaf(x1f, b4.y, fmaf(x0f, a4.y, c4.y)), 0.0f);
            const float hv2 = fmaxf(fmaf(x1f, b4.z, fmaf(x0f, a4.z, c4.z)), 0.0f);
            const float hv3 = fmaxf(fmaf(x1f, b4.w, fmaf(x0f, a4.w, c4.w)), 0.0f);
            const float* r0 = bW2v + h * 12;
            #pragma unroll
            for (int q = 0; q < 3; ++q) {
                const float4 w0 = *reinterpret_cast<const float4*>(r0 + 4 * q);
                const float4 w1 = *reinterpret_cast<const float4*>(r0 + 12 + 4 * q);
                const float4 w2 = *reinterpret_cast<const float4*>(r0 + 24 + 4 * q);
                const float4 w3 = *reinterpret_cast<const float4*>(r0 + 36 + 4 * q);
                acc[4 * q + 0] = fmaf(hv0, w0.x, acc[4 * q + 0]);
                acc[4 * q + 1] = fmaf(hv0, w0.y, acc[4 * q + 1]);
                acc[4 * q + 2] = fmaf(hv0, w0.z, acc[4 * q + 2]);
                acc[4 * q + 3] = fmaf(hv0, w0.w, acc[4 * q + 3]);
                acc[4 * q + 0] = fmaf(hv1, w1.x, acc[4 * q + 0]);
                acc[4 * q + 1] = fmaf(hv1, w1.y, acc[4 * q + 1]);
                acc[4 * q + 2] = fmaf(hv1, w1.z, acc[4 * q + 2]);
                acc[4 * q + 3] = fmaf(hv1, w1.w, acc[4 * q + 3]);
                acc[4 * q + 0] = fmaf(hv2, w2.x, acc[4 * q + 0]);
                acc[4 * q + 1] = fmaf(hv2, w2.y, acc[4 * q + 1]);
                acc[4 * q + 2] = fmaf(hv2, w2.z, acc[4 * q + 2]);
                acc[4 * q + 3] = fmaf(hv2, w2.w, acc[4 * q + 3]);
                acc[4 * q + 0] = fmaf(hv3, w3.x, acc[4 * q + 0]);
                acc[4 * q + 1] = fmaf(hv3, w3.y, acc[4 * q + 1]);
                acc[4 * q + 2] = fmaf(hv3, w3.z, acc[4 * q + 2]);
                acc[4 * q + 3] = fmaf(hv3, w3.w, acc[4 * q + 3]);
            }
        }
    }

    // ---------------- epilogue: gather by sort order, write ----------------
    float r[15];
    r[0]  = p0; r[5] = p1; r[10] = p2;
    r[1]  = sel3f(i0, acc[0], acc[4], acc[8]);
    r[2]  = sel3f(i0, acc[1], acc[5], acc[9]);
    r[3]  = __expf(sel3f(i0, acc[2], acc[6], acc[10]));
    r[4]  = __expf(sel3f(i0, acc[3], acc[7], acc[11]));
    r[6]  = sel3f(i1, acc[0], acc[4], acc[8]);
    r[7]  = sel3f(i1, acc[1], acc[5], acc[9]);
    r[8]  = __expf(sel3f(i1, acc[2], acc[6], acc[10]));
    r[9]  = __expf(sel3f(i1, acc[3], acc[7], acc[11]));
    r[11] = sel3f(i2, acc[0], acc[4], acc[8]);
    r[12] = sel3f(i2, acc[1], acc[5], acc[9]);
    r[13] = __expf(sel3f(i2, acc[2], acc[6], acc[10]));
    r[14] = __expf(sel3f(i2, acc[3], acc[7], acc[11]));

    float* o = out + (size_t)p * 15;
    #pragma unroll
    for (int i = 0; i < 15; ++i) o[i] = r[i];

    out[KJS_OFF + p] = (float)(kj + 1);

    float* mk = out + MASK_OFF + (size_t)p * 3;
    mk[0] = 1.0f;
    mk[1] = (kj >= 1) ? 1.0f : 0.0f;
    mk[2] = (kj >= 2) ? 1.0f : 0.0f;
}

extern "C" void kernel_launch(void* const* d_in, const int* in_sizes, int n_in,
                              void* d_out, int out_size, void* d_ws, size_t ws_size,
                              hipStream_t stream) {
    (void)in_sizes; (void)n_in; (void)d_ws; (void)ws_size; (void)out_size;
    dim3 grid(NBATCH / 128, NJOINT);
    mdn_fused<<<grid, 128, 0, stream>>>(
        (const float*)d_in[0],
        (const float*)d_in[1], (const float*)d_in[2],
        (const float*)d_in[3], (const float*)d_in[4],
        (const float*)d_in[5], (const float*)d_in[6],
        (const float*)d_in[7], (const float*)d_in[8],
        (const float*)d_in[9], (const float*)d_in[10],
        (const float*)d_in[11], (const float*)d_in[12],
        (float*)d_out);
}